// Round 10
// baseline (207.026 us; speedup 1.0000x reference)
//
#include <hip/hip_runtime.h>
#include <hip/hip_bf16.h>

// Problem constants (reference: B=2, S=2048, D=1024, H=16, HD=64)
#define BB 2
#define SS 2048
#define DD 1024
#define HH 16
#define HD 64
#define MM (BB * SS)   // 4096 rows in all GEMMs
#define NQKV 3072      // fused QKV output columns

typedef __attribute__((ext_vector_type(8))) short short8;   // 8 x bf16 frag
typedef __attribute__((ext_vector_type(4))) short s16x4;
typedef __attribute__((ext_vector_type(4))) float floatx4;  // MFMA C/D frag
typedef __attribute__((ext_vector_type(4))) float f32x4;
using bf16 = __hip_bfloat16;

__device__ __forceinline__ float b2f(bf16 x) { return __bfloat162float(x); }
__device__ __forceinline__ short f2bs(float x) {
    bf16 h = __float2bfloat16(x);
    return *reinterpret_cast<short*>(&h);
}
__device__ __forceinline__ float bs2f(short s) {
    bf16 h; *reinterpret_cast<short*>(&h) = s; return __bfloat162float(h);
}

// LDS tiles addressed in 16B chunks (8 shorts), XOR swizzle (chunk ^ (row&7)).
__device__ __forceinline__ int lds_off(int row, int chunk) {
    return row * 64 + ((chunk ^ (row & 7)) * 8);
}

// Direct global->LDS async copy, 16B per lane. LDS dest is wave-uniform base
// + lane*16 (linear); the XOR swizzle is applied on the GLOBAL source address.
#define GL16(gp, lp)                                                        \
    __builtin_amdgcn_global_load_lds(                                       \
        (const __attribute__((address_space(1))) void*)(gp),                \
        (__attribute__((address_space(3))) void*)(lp), 16, 0, 0)

// ---------------------------------------------------------------------------
// Merged converter (r7, unchanged): Wcat | Xb | Wob in ONE launch.
// ---------------------------------------------------------------------------
#define N_WCAT (NQKV * DD / 4)
#define N_X    (MM * DD / 4)
#define N_WOB  (DD * DD / 4)

__global__ __launch_bounds__(256) void convert_all(
    const float* __restrict__ Wq, const float* __restrict__ Wk,
    const float* __restrict__ Wv, const float* __restrict__ X,
    const float* __restrict__ Wo,
    short* __restrict__ wcat, short* __restrict__ xb, short* wob)
{
    const int total = N_WCAT + N_X + (wob ? N_WOB : 0);
    const int stride = gridDim.x * blockDim.x;
    for (int i = blockIdx.x * blockDim.x + threadIdx.x; i < total; i += stride) {
        f32x4 v; short* dp;
        if (i < N_WCAT) {
            const int e = i * 4;
            const int z = e >> 20;
            const int off = e & 0xFFFFF;
            const float* src = (z == 0) ? Wq : (z == 1) ? Wk : Wv;
            v = *(const f32x4*)(src + off);
            dp = wcat + e;
        } else if (i < N_WCAT + N_X) {
            const int e = (i - N_WCAT) * 4;
            v = *(const f32x4*)(X + e);
            dp = xb + e;
        } else {
            const int e = (i - N_WCAT - N_X) * 4;
            v = *(const f32x4*)(Wo + e);
            dp = wob + e;
        }
        s16x4 o; o[0] = f2bs(v[0]); o[1] = f2bs(v[1]); o[2] = f2bs(v[2]); o[3] = f2bs(v[3]);
        *(s16x4*)dp = o;
    }
}

// Fallback single converter (used only when ws is too small to hoist Wob).
__global__ __launch_bounds__(256) void convert_w(
    const float* __restrict__ W, short* __restrict__ dst)
{
    const int stride = gridDim.x * blockDim.x;
    for (int i = blockIdx.x * blockDim.x + threadIdx.x; i < DD * DD / 4; i += stride) {
        f32x4 v = *(const f32x4*)(W + i * 4);
        s16x4 o; o[0] = f2bs(v[0]); o[1] = f2bs(v[1]); o[2] = f2bs(v[2]); o[3] = f2bs(v[3]);
        *(s16x4*)(dst + i * 4) = o;
    }
}

// ---------------------------------------------------------------------------
// Fused QKV GEMM — r7 winner + XCD RECTANGLE mapping (only change: block->
// tile index permutation). Theory: 8200 cyc/K-step vs ~500 of work = L2-fill
// supply bound; default mapping scatters each XCD's 96 co-resident blocks
// across all panels (working set 14.7 MB >> 4 MB L2), so every step's 24 MB
// grid-wide staging misses L2. Rectangle: XCD x owns 8m x 12n panels
// (2 MB A + 3 MB B ~ L2-resident across all 16 K-steps). Bijective:
// mp=(x&3)*8+(loc&7), np=(x>>2)*12+(loc>>3), loc=bid>>3 in [0,96).
// r5's null on this mapping was on the 8-phase structure (schedule-capped);
// never tested on the winning 2-barrier loop.
// ---------------------------------------------------------------------------
__global__ __launch_bounds__(256) void qkv_gemm2(
    const short* __restrict__ Xb, const short* __restrict__ Wcat,
    const float* __restrict__ bq, const float* __restrict__ bk, const float* __restrict__ bv,
    bf16* __restrict__ outQ, bf16* __restrict__ outK, bf16* __restrict__ outV)
{
    __shared__ short As[128 * 64];
    __shared__ short Bs[128 * 64];

    const int tid  = threadIdx.x;
    const int lane = tid & 63;
    const int wave = tid >> 6;
    const int wm   = wave & 1;
    const int wn   = wave >> 1;
    const int g    = lane >> 4;
    const int fr   = lane & 15;

    // XCD rectangle mapping (grid 768 = 32m x 24n tiles of 128^2)
    const int bid = blockIdx.x;
    const int xcd = bid & 7;
    const int loc = bid >> 3;                        // 0..95
    const int m0  = ((xcd & 3) * 8 + (loc & 7)) * 128;   // m-panel 0..31
    const int n0  = ((xcd >> 2) * 12 + (loc >> 3)) * 128; // n-panel 0..23

    const int srow = wave * 32 + (lane >> 3);
    const int schk = (lane & 7) ^ (lane >> 3);
    const short* agl = Xb   + (size_t)(m0 + srow) * DD + schk * 8;
    const short* bgl = Wcat + (size_t)(n0 + srow) * DD + schk * 8;
    short* alds = &As[wave * 32 * 64];
    short* blds = &Bs[wave * 32 * 64];

    floatx4 acc[4][4];
#pragma unroll
    for (int i = 0; i < 4; ++i)
#pragma unroll
        for (int j = 0; j < 4; ++j) acc[i][j] = (floatx4){0.f, 0.f, 0.f, 0.f};

    for (int kb = 0; kb < DD; kb += 64) {
        __syncthreads();
#pragma unroll
        for (int j = 0; j < 4; ++j) {
            GL16(agl + kb + j * 8 * DD, alds + j * 8 * 64);
            GL16(bgl + kb + j * 8 * DD, blds + j * 8 * 64);
        }
        __syncthreads();

#pragma unroll
        for (int kk = 0; kk < 2; ++kk) {
            const int kc = kk * 4 + g;
            short8 af[4], bf[4];
#pragma unroll
            for (int t = 0; t < 4; ++t) {
                af[t] = *(const short8*)&As[lds_off(wm * 64 + t * 16 + fr, kc)];
                bf[t] = *(const short8*)&Bs[lds_off(wn * 64 + t * 16 + fr, kc)];
            }
#pragma unroll
            for (int mt = 0; mt < 4; ++mt)
#pragma unroll
                for (int nt = 0; nt < 4; ++nt)
                    acc[mt][nt] = __builtin_amdgcn_mfma_f32_16x16x32_bf16(
                        af[mt], bf[nt], acc[mt][nt], 0, 0, 0);
        }
    }

#pragma unroll
    for (int nt = 0; nt < 4; ++nt) {
        const int n  = n0 + wn * 64 + nt * 16 + fr;
        const int z  = n >> 10;
        const int nn = n & 1023;
        const int h_ = nn >> 6;
        const int d_ = nn & 63;
        const float biasv = ((z == 0) ? bq : (z == 1) ? bk : bv)[nn];
        bf16* outp = (z == 0) ? outQ : (z == 1) ? outK : outV;
#pragma unroll
        for (int mt = 0; mt < 4; ++mt) {
#pragma unroll
            for (int reg = 0; reg < 4; ++reg) {
                const int m  = m0 + wm * 64 + mt * 16 + g * 4 + reg;
                const int b_ = m >> 11;
                const int s_ = m & (SS - 1);
                const float v = acc[mt][nt][reg] + biasv;
                size_t off;
                if (z == 2) off = ((size_t)((b_ * HH + h_) * HD + d_)) * SS + s_;  // V^T
                else        off = ((size_t)((b_ * HH + h_) * SS + s_)) * HD + d_;  // Q,K
                outp[off] = __float2bfloat16(v);
            }
        }
    }
}

// ---------------------------------------------------------------------------
// Output projection — r7 winner + XCD rectangle (8m x 4n per XCD; grid 256
// = 32m x 8n tiles; bijective: np=(xcd>>2)*4+(loc>>3), loc=bid>>3 in [0,32)).
// ---------------------------------------------------------------------------
__global__ __launch_bounds__(256) void o_gemm2(
    const short* __restrict__ A, const short* __restrict__ Wob,
    const float* __restrict__ bias, float* __restrict__ out)
{
    __shared__ short As[128 * 64];
    __shared__ short Bs[128 * 64];

    const int tid  = threadIdx.x;
    const int lane = tid & 63;
    const int wave = tid >> 6;
    const int wm   = wave & 1;
    const int wn   = wave >> 1;
    const int g    = lane >> 4;
    const int fr   = lane & 15;

    const int bid = blockIdx.x;
    const int xcd = bid & 7;
    const int loc = bid >> 3;                        // 0..31
    const int m0  = ((xcd & 3) * 8 + (loc & 7)) * 128;   // m-panel 0..31
    const int n0  = ((xcd >> 2) * 4 + (loc >> 3)) * 128; // n-panel 0..7

    const int srow = wave * 32 + (lane >> 3);
    const int schk = (lane & 7) ^ (lane >> 3);
    const short* agl = A   + (size_t)(m0 + srow) * DD + schk * 8;
    const short* bgl = Wob + (size_t)(n0 + srow) * DD + schk * 8;
    short* alds = &As[wave * 32 * 64];
    short* blds = &Bs[wave * 32 * 64];

    floatx4 acc[4][4];
#pragma unroll
    for (int i = 0; i < 4; ++i)
#pragma unroll
        for (int j = 0; j < 4; ++j) acc[i][j] = (floatx4){0.f, 0.f, 0.f, 0.f};

    for (int kb = 0; kb < DD; kb += 64) {
        __syncthreads();
#pragma unroll
        for (int j = 0; j < 4; ++j) {
            GL16(agl + kb + j * 8 * DD, alds + j * 8 * 64);
            GL16(bgl + kb + j * 8 * DD, blds + j * 8 * 64);
        }
        __syncthreads();

#pragma unroll
        for (int kk = 0; kk < 2; ++kk) {
            const int kc = kk * 4 + g;
            short8 af[4], bf[4];
#pragma unroll
            for (int t = 0; t < 4; ++t) {
                af[t] = *(const short8*)&As[lds_off(wm * 64 + t * 16 + fr, kc)];
                bf[t] = *(const short8*)&Bs[lds_off(wn * 64 + t * 16 + fr, kc)];
            }
#pragma unroll
            for (int mt = 0; mt < 4; ++mt)
#pragma unroll
                for (int nt = 0; nt < 4; ++nt)
                    acc[mt][nt] = __builtin_amdgcn_mfma_f32_16x16x32_bf16(
                        af[mt], bf[nt], acc[mt][nt], 0, 0, 0);
        }
    }

#pragma unroll
    for (int nt = 0; nt < 4; ++nt) {
        const int n = n0 + wn * 64 + nt * 16 + fr;
        const float biasv = bias[n];
#pragma unroll
        for (int mt = 0; mt < 4; ++mt) {
#pragma unroll
            for (int reg = 0; reg < 4; ++reg) {
                const int m = m0 + wm * 64 + mt * 16 + g * 4 + reg;
                out[(size_t)m * DD + n] = acc[mt][nt][reg] + biasv;
            }
        }
    }
}

// ---------------------------------------------------------------------------
// MFMA flash attention v7 + setprio (r9, unchanged).
// ---------------------------------------------------------------------------
__global__ __launch_bounds__(256) void flash_mfma7(
    const bf16* __restrict__ Qh,   // [B,H,S,HD]
    const bf16* __restrict__ Kh,   // [B,H,S,HD]
    const bf16* __restrict__ VT,   // [B,H,HD,S]
    const int*  __restrict__ pad,  // [B,S] int32, nonzero = masked key
    bf16* __restrict__ attn)       // [B,S,D]
{
    __shared__ short Ks[2][64 * 64];    // 16 KB (double-buffered)
    __shared__ short Vs[2][64 * 64];    // 16 KB
    __shared__ short Pld[4][16 * 64];   // 8 KB per-wave P tiles

    const int tid  = threadIdx.x;
    const int lane = tid & 63;
    const int wave = tid >> 6;
    const int xcd = blockIdx.x & 7;
    const int idx = blockIdx.x >> 3;        // 0..127
    const int bh  = (xcd << 2) | (idx & 3); // 4 heads per XCD group
    const int qt  = 31 - (idx >> 2);        // 64-row q-tile, longest first
    const int q0  = qt * 64 + wave * 16;
    const int b_  = bh >> 4;
    const int h_  = bh & 15;

    const int g  = lane >> 4;   // 0..3
    const int fr = lane & 15;
    const int k8 = g * 8;

    short* myP = Pld[wave];

    // Q fragments (2 dim-halves), pre-scaled by 1/sqrt(64)=0.125
    const bf16* qbase = Qh + ((size_t)bh * SS + q0 + fr) * HD + k8;
    short8 qf[2];
#pragma unroll
    for (int hh = 0; hh < 2; ++hh) {
        short8 rawq = *(const short8*)((const short*)qbase + hh * 32);
#pragma unroll
        for (int j = 0; j < 8; ++j) qf[hh][j] = f2bs(bs2f(rawq[j]) * 0.125f);
    }

    const int* padrow = pad + b_ * SS;
    const short* kbh = (const short*)(Kh + (size_t)bh * SS * HD);
    const short* vbh = (const short*)(VT + (size_t)bh * HD * SS);

    const int l8  = lane >> 3;          // 0..7
    const int sch = (lane & 7) ^ l8;    // pre-swizzled source chunk
    auto stageKV = [&](int buf, int kb) {
#pragma unroll
        for (int j = 0; j < 2; ++j) {
            const int r = wave * 16 + j * 8;          // wave-uniform base row
            GL16(kbh + (size_t)(kb + r + l8) * HD + sch * 8, &Ks[buf][r * 64]);
            GL16(vbh + (size_t)(r + l8) * SS + kb + sch * 8, &Vs[buf][r * 64]);
        }
    };

    floatx4 o[4] = {{0,0,0,0},{0,0,0,0},{0,0,0,0},{0,0,0,0}};
    float l_acc[4] = {0.f, 0.f, 0.f, 0.f};

    const int kend = qt * 64 + 63;   // uniform across the block

    stageKV(0, 0);
    asm volatile("s_waitcnt vmcnt(0)" ::: "memory");
    __syncthreads();

    for (int kb = 0; kb <= kend; kb += 64) {
        const int cur = (kb >> 6) & 1;
        if (kb + 64 <= kend) stageKV(cur ^ 1, kb + 64);

        const short* Kc = Ks[cur];
        const short* Vc = Vs[cur];

        floatx4 c[4];
        __builtin_amdgcn_s_setprio(1);
#pragma unroll
        for (int t = 0; t < 4; ++t) {
            short8 kf0 = *(const short8*)&Kc[(t * 16 + fr) * 64 + ((g       ^ (fr & 7)) << 3)];
            short8 kf1 = *(const short8*)&Kc[(t * 16 + fr) * 64 + (((g + 4) ^ (fr & 7)) << 3)];
            floatx4 cc = {0, 0, 0, 0};
            cc = __builtin_amdgcn_mfma_f32_16x16x32_bf16(qf[0], kf0, cc, 0, 0, 0);
            cc = __builtin_amdgcn_mfma_f32_16x16x32_bf16(qf[1], kf1, cc, 0, 0, 0);
            c[t] = cc;
        }
        __builtin_amdgcn_s_setprio(0);

        bool pm[4];
#pragma unroll
        for (int t = 0; t < 4; ++t) pm[t] = (padrow[kb + t * 16 + fr] != 0);

#pragma unroll
        for (int reg = 0; reg < 4; ++reg) {
            const int q   = q0 + g * 4 + reg;
            const int row = g * 4 + reg;
#pragma unroll
            for (int t = 0; t < 4; ++t) {
                const int key = kb + t * 16 + fr;
                const float p = (key <= q && !pm[t]) ? __expf(c[t][reg]) : 0.f;
                l_acc[reg] += p;
                const int col = t * 16 + fr;
                myP[row * 64 + (((col >> 3) ^ (row & 7)) << 3) + (col & 7)] = f2bs(p);
            }
        }

        short8 pf0 = *(const short8*)&myP[fr * 64 + ((g       ^ (fr & 7)) << 3)];
        short8 pf1 = *(const short8*)&myP[fr * 64 + (((g + 4) ^ (fr & 7)) << 3)];
        __builtin_amdgcn_s_setprio(1);
#pragma unroll
        for (int n = 0; n < 4; ++n) {
            short8 vf0 = *(const short8*)&Vc[(n * 16 + fr) * 64 + ((g       ^ (fr & 7)) << 3)];
            short8 vf1 = *(const short8*)&Vc[(n * 16 + fr) * 64 + (((g + 4) ^ (fr & 7)) << 3)];
            o[n] = __builtin_amdgcn_mfma_f32_16x16x32_bf16(pf0, vf0, o[n], 0, 0, 0);
            o[n] = __builtin_amdgcn_mfma_f32_16x16x32_bf16(pf1, vf1, o[n], 0, 0, 0);
        }
        __builtin_amdgcn_s_setprio(0);

        asm volatile("s_waitcnt vmcnt(0)" ::: "memory");
        __syncthreads();
    }

    float inv[4];
#pragma unroll
    for (int reg = 0; reg < 4; ++reg) {
        float l = l_acc[reg];
#pragma unroll
        for (int off = 1; off < 16; off <<= 1) l += __shfl_xor(l, off);
        inv[reg] = 1.f / fmaxf(l, 1e-38f);
    }
#pragma unroll
    for (int n = 0; n < 4; ++n) {
#pragma unroll
        for (int reg = 0; reg < 4; ++reg) {
            const int q = q0 + g * 4 + reg;
            attn[((size_t)(b_ * SS + q)) * DD + h_ * HD + n * 16 + fr] =
                __float2bfloat16(o[n][reg] * inv[reg]);
        }
    }
}

// ---------------------------------------------------------------------------
extern "C" void kernel_launch(void* const* d_in, const int* in_sizes, int n_in,
                              void* d_out, int out_size, void* d_ws, size_t ws_size,
                              hipStream_t stream) {
    const float* x   = (const float*)d_in[0];
    const int*   pad = (const int*)  d_in[1];
    const float* Wq  = (const float*)d_in[2];
    const float* bq  = (const float*)d_in[3];
    const float* Wk  = (const float*)d_in[4];
    const float* bk  = (const float*)d_in[5];
    const float* Wv  = (const float*)d_in[6];
    const float* bv  = (const float*)d_in[7];
    const float* Wo  = (const float*)d_in[8];
    const float* bo  = (const float*)d_in[9];
    float* out = (float*)d_out;                  // fp32 output

    const size_t NELEM = (size_t)BB * HH * SS * HD;  // 4,194,304
    bf16* Qh   = (bf16*)d_ws;
    bf16* Kh   = Qh + NELEM;
    bf16* VT   = Kh + NELEM;
    bf16* attn = VT + NELEM;
    // Scratch in d_out (16.78 MB): Wcat 6.29 MB + Xb 8.39 MB, both consumed
    // before o_gemm2 overwrites d_out with the final fp32 result.
    short* Wcat = (short*)d_out;
    short* Xb   = (short*)d_out + (size_t)NQKV * DD;

    // Wob: hoist into ws tail if it fits (single merged convert, 4 launches);
    // else alias Qh and convert after flash (fallback).
    const size_t ws_need = 4 * NELEM * sizeof(bf16) + (size_t)DD * DD * sizeof(short);
    const bool big_ws = ws_size >= ws_need;
    short* Wob = big_ws ? (short*)(attn + NELEM) : (short*)Qh;

    convert_all<<<2048, 256, 0, stream>>>(Wq, Wk, Wv, x, Wo, Wcat, Xb,
                                          big_ws ? Wob : nullptr);

    qkv_gemm2<<<768, 256, 0, stream>>>(Xb, Wcat, bq, bk, bv, Qh, Kh, VT);

    flash_mfma7<<<BB * HH * 32, 256, 0, stream>>>(Qh, Kh, VT, pad, attn);

    if (!big_ws) convert_w<<<512, 256, 0, stream>>>(Wo, Wob);

    o_gemm2<<<256, 256, 0, stream>>>((const short*)attn, Wob, bo, out);
}

// Round 11
// 200.261 us; speedup vs baseline: 1.0338x; 1.0338x over previous
//
#include <hip/hip_runtime.h>
#include <hip/hip_bf16.h>

// Problem constants (reference: B=2, S=2048, D=1024, H=16, HD=64)
#define BB 2
#define SS 2048
#define DD 1024
#define HH 16
#define HD 64
#define MM (BB * SS)   // 4096 rows in all GEMMs
#define NQKV 3072      // fused QKV output columns

typedef __attribute__((ext_vector_type(8))) short short8;   // 8 x bf16 frag
typedef __attribute__((ext_vector_type(4))) short s16x4;
typedef __attribute__((ext_vector_type(4))) float floatx4;  // MFMA C/D frag
typedef __attribute__((ext_vector_type(4))) float f32x4;
using bf16 = __hip_bfloat16;

__device__ __forceinline__ float b2f(bf16 x) { return __bfloat162float(x); }
__device__ __forceinline__ short f2bs(float x) {
    bf16 h = __float2bfloat16(x);
    return *reinterpret_cast<short*>(&h);
}
__device__ __forceinline__ float bs2f(short s) {
    bf16 h; *reinterpret_cast<short*>(&h) = s; return __bfloat162float(h);
}

// LDS tiles addressed in 16B chunks (8 shorts), XOR swizzle (chunk ^ (row&7)).
__device__ __forceinline__ int lds_off(int row, int chunk) {
    return row * 64 + ((chunk ^ (row & 7)) * 8);
}

// Direct global->LDS async copy, 16B per lane. LDS dest is wave-uniform base
// + lane*16 (linear); the XOR swizzle is applied on the GLOBAL source address.
#define GL16(gp, lp)                                                        \
    __builtin_amdgcn_global_load_lds(                                       \
        (const __attribute__((address_space(1))) void*)(gp),                \
        (__attribute__((address_space(3))) void*)(lp), 16, 0, 0)

// ---------------------------------------------------------------------------
// Merged converter (r7, unchanged): Wcat | Xb | Wob in ONE launch.
// ---------------------------------------------------------------------------
#define N_WCAT (NQKV * DD / 4)
#define N_X    (MM * DD / 4)
#define N_WOB  (DD * DD / 4)

__global__ __launch_bounds__(256) void convert_all(
    const float* __restrict__ Wq, const float* __restrict__ Wk,
    const float* __restrict__ Wv, const float* __restrict__ X,
    const float* __restrict__ Wo,
    short* __restrict__ wcat, short* __restrict__ xb, short* wob)
{
    const int total = N_WCAT + N_X + (wob ? N_WOB : 0);
    const int stride = gridDim.x * blockDim.x;
    for (int i = blockIdx.x * blockDim.x + threadIdx.x; i < total; i += stride) {
        f32x4 v; short* dp;
        if (i < N_WCAT) {
            const int e = i * 4;
            const int z = e >> 20;
            const int off = e & 0xFFFFF;
            const float* src = (z == 0) ? Wq : (z == 1) ? Wk : Wv;
            v = *(const f32x4*)(src + off);
            dp = wcat + e;
        } else if (i < N_WCAT + N_X) {
            const int e = (i - N_WCAT) * 4;
            v = *(const f32x4*)(X + e);
            dp = xb + e;
        } else {
            const int e = (i - N_WCAT - N_X) * 4;
            v = *(const f32x4*)(Wo + e);
            dp = wob + e;
        }
        s16x4 o; o[0] = f2bs(v[0]); o[1] = f2bs(v[1]); o[2] = f2bs(v[2]); o[3] = f2bs(v[3]);
        *(s16x4*)dp = o;
    }
}

// Fallback single converter (used only when ws is too small to hoist Wob).
__global__ __launch_bounds__(256) void convert_w(
    const float* __restrict__ W, short* __restrict__ dst)
{
    const int stride = gridDim.x * blockDim.x;
    for (int i = blockIdx.x * blockDim.x + threadIdx.x; i < DD * DD / 4; i += stride) {
        f32x4 v = *(const f32x4*)(W + i * 4);
        s16x4 o; o[0] = f2bs(v[0]); o[1] = f2bs(v[1]); o[2] = f2bs(v[2]); o[3] = f2bs(v[3]);
        *(s16x4*)(dst + i * 4) = o;
    }
}

// ---------------------------------------------------------------------------
// Fused QKV GEMM, r19: 128M x 64N tile -> grid 1536, SIX blocks/CU (was 3).
// Six variants (schedule/dbuf/mapping) were all duration-invariant at 54.5 us
// with MfmaUtil 18% — the structure is carried by inter-block overlap (m114)
// and 3 lockstep blocks/CU starve it. Guideline-1 lever, never touched.
// LDS: A 16 KB + B 8 KB = 24 KB (6x24=144 <= 160). acc 4x2 (32 VGPR);
// __launch_bounds__(256,6) caps VGPR at 85 to guarantee 6 waves/SIMD.
// Same validated 2-barrier loop, staging, swizzle, epilogue formulas.
// ---------------------------------------------------------------------------
__global__ __launch_bounds__(256, 6) void qkv_gemm2(
    const short* __restrict__ Xb, const short* __restrict__ Wcat,
    const float* __restrict__ bq, const float* __restrict__ bk, const float* __restrict__ bv,
    bf16* __restrict__ outQ, bf16* __restrict__ outK, bf16* __restrict__ outV)
{
    __shared__ short As[128 * 64];   // 16 KB
    __shared__ short Bs[64 * 64];    // 8 KB

    const int tid  = threadIdx.x;
    const int lane = tid & 63;
    const int wave = tid >> 6;
    const int wm   = wave & 1;     // M half (64 rows)
    const int wn   = wave >> 1;    // N quarter (32 cols)... wn in 0..1? no:
    // 4 waves: wm = wave&1 (M 64-half), wn = wave>>1 in 0..1 (N 32-half)
    const int g    = lane >> 4;
    const int fr   = lane & 15;

    const int m0 = blockIdx.x * 128;
    const int n0 = blockIdx.y * 64;

    const int l8  = lane >> 3;           // 0..7
    const int sch = (lane & 7) ^ l8;     // pre-swizzled source chunk
    const short* agl = Xb   + (size_t)(m0 + l8) * DD + sch * 8;
    const short* bgl = Wcat + (size_t)(n0 + l8) * DD + sch * 8;

    floatx4 acc[4][2];
#pragma unroll
    for (int i = 0; i < 4; ++i)
#pragma unroll
        for (int j = 0; j < 2; ++j) acc[i][j] = (floatx4){0.f, 0.f, 0.f, 0.f};

    for (int kb = 0; kb < DD; kb += 64) {
        __syncthreads();   // prior iteration's LDS reads complete
        // A: wave covers rows [wave*32, +32), 4 GL16/thread
#pragma unroll
        for (int j = 0; j < 4; ++j) {
            const int r = wave * 32 + j * 8;
            GL16(agl + (size_t)r * DD + kb, &As[r * 64]);
        }
        // B: wave covers rows [wave*16, +16), 2 GL16/thread
#pragma unroll
        for (int j = 0; j < 2; ++j) {
            const int r = wave * 16 + j * 8;
            GL16(bgl + (size_t)r * DD + kb, &Bs[r * 64]);
        }
        __syncthreads();   // compiler drains vmcnt before s_barrier

#pragma unroll
        for (int kk = 0; kk < 2; ++kk) {
            const int kc = kk * 4 + g;
            short8 af[4], bf[2];
#pragma unroll
            for (int t = 0; t < 4; ++t)
                af[t] = *(const short8*)&As[lds_off(wm * 64 + t * 16 + fr, kc)];
#pragma unroll
            for (int u = 0; u < 2; ++u)
                bf[u] = *(const short8*)&Bs[lds_off(wn * 32 + u * 16 + fr, kc)];
#pragma unroll
            for (int mt = 0; mt < 4; ++mt)
#pragma unroll
                for (int nt = 0; nt < 2; ++nt)
                    acc[mt][nt] = __builtin_amdgcn_mfma_f32_16x16x32_bf16(
                        af[mt], bf[nt], acc[mt][nt], 0, 0, 0);
        }
    }

#pragma unroll
    for (int nt = 0; nt < 2; ++nt) {
        const int n  = n0 + wn * 32 + nt * 16 + fr;
        const int z  = n >> 10;
        const int nn = n & 1023;
        const int h_ = nn >> 6;
        const int d_ = nn & 63;
        const float biasv = ((z == 0) ? bq : (z == 1) ? bk : bv)[nn];
        bf16* outp = (z == 0) ? outQ : (z == 1) ? outK : outV;
#pragma unroll
        for (int mt = 0; mt < 4; ++mt) {
#pragma unroll
            for (int reg = 0; reg < 4; ++reg) {
                const int m  = m0 + wm * 64 + mt * 16 + g * 4 + reg;
                const int b_ = m >> 11;
                const int s_ = m & (SS - 1);
                const float v = acc[mt][nt][reg] + biasv;
                size_t off;
                if (z == 2) off = ((size_t)((b_ * HH + h_) * HD + d_)) * SS + s_;  // V^T
                else        off = ((size_t)((b_ * HH + h_) * SS + s_)) * HD + d_;  // Q,K
                outp[off] = __float2bfloat16(v);
            }
        }
    }
}

// ---------------------------------------------------------------------------
// Output projection, r19: 128M x 64N tile -> grid 512, 2 blocks/CU (was 1).
// ---------------------------------------------------------------------------
__global__ __launch_bounds__(256, 6) void o_gemm2(
    const short* __restrict__ A, const short* __restrict__ Wob,
    const float* __restrict__ bias, float* __restrict__ out)
{
    __shared__ short As[128 * 64];
    __shared__ short Bs[64 * 64];

    const int tid  = threadIdx.x;
    const int lane = tid & 63;
    const int wave = tid >> 6;
    const int wm   = wave & 1;
    const int wn   = wave >> 1;
    const int g    = lane >> 4;
    const int fr   = lane & 15;

    const int m0 = blockIdx.x * 128;
    const int n0 = blockIdx.y * 64;

    const int l8  = lane >> 3;
    const int sch = (lane & 7) ^ l8;
    const short* agl = A   + (size_t)(m0 + l8) * DD + sch * 8;
    const short* bgl = Wob + (size_t)(n0 + l8) * DD + sch * 8;

    floatx4 acc[4][2];
#pragma unroll
    for (int i = 0; i < 4; ++i)
#pragma unroll
        for (int j = 0; j < 2; ++j) acc[i][j] = (floatx4){0.f, 0.f, 0.f, 0.f};

    for (int kb = 0; kb < DD; kb += 64) {
        __syncthreads();
#pragma unroll
        for (int j = 0; j < 4; ++j) {
            const int r = wave * 32 + j * 8;
            GL16(agl + (size_t)r * DD + kb, &As[r * 64]);
        }
#pragma unroll
        for (int j = 0; j < 2; ++j) {
            const int r = wave * 16 + j * 8;
            GL16(bgl + (size_t)r * DD + kb, &Bs[r * 64]);
        }
        __syncthreads();

#pragma unroll
        for (int kk = 0; kk < 2; ++kk) {
            const int kc = kk * 4 + g;
            short8 af[4], bf[2];
#pragma unroll
            for (int t = 0; t < 4; ++t)
                af[t] = *(const short8*)&As[lds_off(wm * 64 + t * 16 + fr, kc)];
#pragma unroll
            for (int u = 0; u < 2; ++u)
                bf[u] = *(const short8*)&Bs[lds_off(wn * 32 + u * 16 + fr, kc)];
#pragma unroll
            for (int mt = 0; mt < 4; ++mt)
#pragma unroll
                for (int nt = 0; nt < 2; ++nt)
                    acc[mt][nt] = __builtin_amdgcn_mfma_f32_16x16x32_bf16(
                        af[mt], bf[nt], acc[mt][nt], 0, 0, 0);
        }
    }

#pragma unroll
    for (int nt = 0; nt < 2; ++nt) {
        const int n = n0 + wn * 32 + nt * 16 + fr;
        const float biasv = bias[n];
#pragma unroll
        for (int mt = 0; mt < 4; ++mt) {
#pragma unroll
            for (int reg = 0; reg < 4; ++reg) {
                const int m = m0 + wm * 64 + mt * 16 + g * 4 + reg;
                out[(size_t)m * DD + n] = acc[mt][nt][reg] + biasv;
            }
        }
    }
}

// ---------------------------------------------------------------------------
// MFMA flash attention v7 + setprio (r9, unchanged).
// ---------------------------------------------------------------------------
__global__ __launch_bounds__(256) void flash_mfma7(
    const bf16* __restrict__ Qh,   // [B,H,S,HD]
    const bf16* __restrict__ Kh,   // [B,H,S,HD]
    const bf16* __restrict__ VT,   // [B,H,HD,S]
    const int*  __restrict__ pad,  // [B,S] int32, nonzero = masked key
    bf16* __restrict__ attn)       // [B,S,D]
{
    __shared__ short Ks[2][64 * 64];    // 16 KB (double-buffered)
    __shared__ short Vs[2][64 * 64];    // 16 KB
    __shared__ short Pld[4][16 * 64];   // 8 KB per-wave P tiles

    const int tid  = threadIdx.x;
    const int lane = tid & 63;
    const int wave = tid >> 6;
    const int xcd = blockIdx.x & 7;
    const int idx = blockIdx.x >> 3;        // 0..127
    const int bh  = (xcd << 2) | (idx & 3); // 4 heads per XCD group
    const int qt  = 31 - (idx >> 2);        // 64-row q-tile, longest first
    const int q0  = qt * 64 + wave * 16;
    const int b_  = bh >> 4;
    const int h_  = bh & 15;

    const int g  = lane >> 4;   // 0..3
    const int fr = lane & 15;
    const int k8 = g * 8;

    short* myP = Pld[wave];

    // Q fragments (2 dim-halves), pre-scaled by 1/sqrt(64)=0.125
    const bf16* qbase = Qh + ((size_t)bh * SS + q0 + fr) * HD + k8;
    short8 qf[2];
#pragma unroll
    for (int hh = 0; hh < 2; ++hh) {
        short8 rawq = *(const short8*)((const short*)qbase + hh * 32);
#pragma unroll
        for (int j = 0; j < 8; ++j) qf[hh][j] = f2bs(bs2f(rawq[j]) * 0.125f);
    }

    const int* padrow = pad + b_ * SS;
    const short* kbh = (const short*)(Kh + (size_t)bh * SS * HD);
    const short* vbh = (const short*)(VT + (size_t)bh * HD * SS);

    const int l8  = lane >> 3;          // 0..7
    const int sch = (lane & 7) ^ l8;    // pre-swizzled source chunk
    auto stageKV = [&](int buf, int kb) {
#pragma unroll
        for (int j = 0; j < 2; ++j) {
            const int r = wave * 16 + j * 8;          // wave-uniform base row
            GL16(kbh + (size_t)(kb + r + l8) * HD + sch * 8, &Ks[buf][r * 64]);
            GL16(vbh + (size_t)(r + l8) * SS + kb + sch * 8, &Vs[buf][r * 64]);
        }
    };

    floatx4 o[4] = {{0,0,0,0},{0,0,0,0},{0,0,0,0},{0,0,0,0}};
    float l_acc[4] = {0.f, 0.f, 0.f, 0.f};

    const int kend = qt * 64 + 63;   // uniform across the block

    stageKV(0, 0);
    asm volatile("s_waitcnt vmcnt(0)" ::: "memory");
    __syncthreads();

    for (int kb = 0; kb <= kend; kb += 64) {
        const int cur = (kb >> 6) & 1;
        if (kb + 64 <= kend) stageKV(cur ^ 1, kb + 64);

        const short* Kc = Ks[cur];
        const short* Vc = Vs[cur];

        floatx4 c[4];
        __builtin_amdgcn_s_setprio(1);
#pragma unroll
        for (int t = 0; t < 4; ++t) {
            short8 kf0 = *(const short8*)&Kc[(t * 16 + fr) * 64 + ((g       ^ (fr & 7)) << 3)];
            short8 kf1 = *(const short8*)&Kc[(t * 16 + fr) * 64 + (((g + 4) ^ (fr & 7)) << 3)];
            floatx4 cc = {0, 0, 0, 0};
            cc = __builtin_amdgcn_mfma_f32_16x16x32_bf16(qf[0], kf0, cc, 0, 0, 0);
            cc = __builtin_amdgcn_mfma_f32_16x16x32_bf16(qf[1], kf1, cc, 0, 0, 0);
            c[t] = cc;
        }
        __builtin_amdgcn_s_setprio(0);

        bool pm[4];
#pragma unroll
        for (int t = 0; t < 4; ++t) pm[t] = (padrow[kb + t * 16 + fr] != 0);

#pragma unroll
        for (int reg = 0; reg < 4; ++reg) {
            const int q   = q0 + g * 4 + reg;
            const int row = g * 4 + reg;
#pragma unroll
            for (int t = 0; t < 4; ++t) {
                const int key = kb + t * 16 + fr;
                const float p = (key <= q && !pm[t]) ? __expf(c[t][reg]) : 0.f;
                l_acc[reg] += p;
                const int col = t * 16 + fr;
                myP[row * 64 + (((col >> 3) ^ (row & 7)) << 3) + (col & 7)] = f2bs(p);
            }
        }

        short8 pf0 = *(const short8*)&myP[fr * 64 + ((g       ^ (fr & 7)) << 3)];
        short8 pf1 = *(const short8*)&myP[fr * 64 + (((g + 4) ^ (fr & 7)) << 3)];
        __builtin_amdgcn_s_setprio(1);
#pragma unroll
        for (int n = 0; n < 4; ++n) {
            short8 vf0 = *(const short8*)&Vc[(n * 16 + fr) * 64 + ((g       ^ (fr & 7)) << 3)];
            short8 vf1 = *(const short8*)&Vc[(n * 16 + fr) * 64 + (((g + 4) ^ (fr & 7)) << 3)];
            o[n] = __builtin_amdgcn_mfma_f32_16x16x32_bf16(pf0, vf0, o[n], 0, 0, 0);
            o[n] = __builtin_amdgcn_mfma_f32_16x16x32_bf16(pf1, vf1, o[n], 0, 0, 0);
        }
        __builtin_amdgcn_s_setprio(0);

        asm volatile("s_waitcnt vmcnt(0)" ::: "memory");
        __syncthreads();
    }

    float inv[4];
#pragma unroll
    for (int reg = 0; reg < 4; ++reg) {
        float l = l_acc[reg];
#pragma unroll
        for (int off = 1; off < 16; off <<= 1) l += __shfl_xor(l, off);
        inv[reg] = 1.f / fmaxf(l, 1e-38f);
    }
#pragma unroll
    for (int n = 0; n < 4; ++n) {
#pragma unroll
        for (int reg = 0; reg < 4; ++reg) {
            const int q = q0 + g * 4 + reg;
            attn[((size_t)(b_ * SS + q)) * DD + h_ * HD + n * 16 + fr] =
                __float2bfloat16(o[n][reg] * inv[reg]);
        }
    }
}

// ---------------------------------------------------------------------------
extern "C" void kernel_launch(void* const* d_in, const int* in_sizes, int n_in,
                              void* d_out, int out_size, void* d_ws, size_t ws_size,
                              hipStream_t stream) {
    const float* x   = (const float*)d_in[0];
    const int*   pad = (const int*)  d_in[1];
    const float* Wq  = (const float*)d_in[2];
    const float* bq  = (const float*)d_in[3];
    const float* Wk  = (const float*)d_in[4];
    const float* bk  = (const float*)d_in[5];
    const float* Wv  = (const float*)d_in[6];
    const float* bv  = (const float*)d_in[7];
    const float* Wo  = (const float*)d_in[8];
    const float* bo  = (const float*)d_in[9];
    float* out = (float*)d_out;                  // fp32 output

    const size_t NELEM = (size_t)BB * HH * SS * HD;  // 4,194,304
    bf16* Qh   = (bf16*)d_ws;
    bf16* Kh   = Qh + NELEM;
    bf16* VT   = Kh + NELEM;
    bf16* attn = VT + NELEM;
    // Scratch in d_out (16.78 MB): Wcat 6.29 MB + Xb 8.39 MB, both consumed
    // before o_gemm2 overwrites d_out with the final fp32 result.
    short* Wcat = (short*)d_out;
    short* Xb   = (short*)d_out + (size_t)NQKV * DD;

    // Wob: hoist into ws tail if it fits (single merged convert, 4 launches);
    // else alias Qh and convert after flash (fallback).
    const size_t ws_need = 4 * NELEM * sizeof(bf16) + (size_t)DD * DD * sizeof(short);
    const bool big_ws = ws_size >= ws_need;
    short* Wob = big_ws ? (short*)(attn + NELEM) : (short*)Qh;

    convert_all<<<2048, 256, 0, stream>>>(Wq, Wk, Wv, x, Wo, Wcat, Xb,
                                          big_ws ? Wob : nullptr);

    dim3 gq(MM / 128, NQKV / 64);
    qkv_gemm2<<<gq, 256, 0, stream>>>(Xb, Wcat, bq, bk, bv, Qh, Kh, VT);

    flash_mfma7<<<BB * HH * 32, 256, 0, stream>>>(Qh, Kh, VT, pad, attn);

    if (!big_ws) convert_w<<<512, 256, 0, stream>>>(Wo, Wob);

    dim3 go(MM / 128, DD / 64);
    o_gemm2<<<go, 256, 0, stream>>>((const short*)attn, Wob, bo, out);
}